// Round 9
// baseline (176.404 us; speedup 1.0000x reference)
//
#include <hip/hip_runtime.h>
#include <hip/hip_bf16.h>
#include <hip/hip_fp16.h>
#include <cstdint>

typedef __attribute__((ext_vector_type(8))) short s16x8;
typedef __attribute__((ext_vector_type(4))) short s16x4;
typedef __attribute__((ext_vector_type(8))) _Float16 f16x8;
typedef __attribute__((ext_vector_type(4))) _Float16 f16x4;
typedef __attribute__((ext_vector_type(4))) float f32x4;

__device__ __forceinline__ void gload16(const void* g, void* l){
  __builtin_amdgcn_global_load_lds((const __attribute__((address_space(1))) void*)g,
                                   (__attribute__((address_space(3))) void*)l, 16, 0, 0);
}

// ---------------- pre-pass: fp32 -> fp16 ----------------
__global__ void convert_f16(const float* __restrict__ in, ushort* __restrict__ out, int n4){
  int i = blockIdx.x * blockDim.x + threadIdx.x;
  if (i >= n4) return;
  const f32x4 v = ((const f32x4*)in)[i];
  f16x4 o;
#pragma unroll
  for (int j = 0; j < 4; ++j) o[j] = (_Float16)v[j];
  ((f16x4*)out)[i] = o;
}

// transpose + convert: in[K][N] f32 -> outT[N][K] fp16
__global__ void transpose_f16(const float* __restrict__ in, ushort* __restrict__ outT,
                              int K, int N){
  __shared__ float tile[32][33];
  const int kb = blockIdx.y * 32, nb = blockIdx.x * 32;
  const int tx = threadIdx.x & 31, ty = threadIdx.x >> 5;  // ty: 0..7
#pragma unroll
  for (int r = 0; r < 32; r += 8)
    tile[ty + r][tx] = in[(size_t)(kb + ty + r) * N + nb + tx];
  __syncthreads();
#pragma unroll
  for (int r = 0; r < 32; r += 8){
    const float v = tile[tx][ty + r];
    const _Float16 h = (_Float16)v;
    outT[(size_t)(nb + ty + r) * K + kb + tx] = __builtin_bit_cast(ushort, h);
  }
}

// W3 (512x10 f32) -> W3T (10x512 f32)
__global__ void transpose_w3(const float* __restrict__ W3, float* __restrict__ W3T){
  const int k = threadIdx.x;  // 512 threads
#pragma unroll
  for (int c = 0; c < 10; ++c) W3T[c * 512 + k] = W3[k * 10 + c];
}

// ---- 256x256-tile fp16 GEMM: 1 barrier/K-tile, read-once fragments -----------
// 8 waves (2M x 4N), per-wave 128x64 output. LDS 128 KB double-buffered:
//   A plane p at hw p*16384 (half mh at +mh*8192), B at 32768 + p*16384.
// Per K-tile u (plane par=u&1):
//   vmcnt(0)                  // tile-u stages (issued 1 tile ago) landed: free
//   s_barrier                 // publish u; WAR-safe (all prior reads drained)
//   24 ds_read_b128           // af0[8] bf0[4] af1[8] bf1[4] - each frag ONCE
//   8 global_load_lds         // all 4 halves of tile u+1 -> other plane
//   sched_barrier(0)
//   64 MFMA                   // compiler inserts minimal lgkm waits; ks1 reads
//                             // stream under the ks0 MFMA cluster
// Last tile wrap-stages tile 0 (harmless); __syncthreads drains before epilogue.
template<int MODE>
__global__ __launch_bounds__(512, 2)
void gemm_f16_256(const ushort* __restrict__ A, const ushort* __restrict__ Bw,
                  const float* __restrict__ bias, ushort* __restrict__ out,
                  int N, int K)
{
  __shared__ ushort lds[65536];
  const int t = threadIdx.x;
  const int lane = t & 63;
  const int w = t >> 6;
  const int wm = w >> 2, wn = w & 3;       // wave grid 2(M) x 4(N)
  const int ln15 = lane & 15, lnHi = lane >> 4;

  // XCD-aware bijective swizzle (nwg divisible by 8)
  const int gx = gridDim.x;
  const int nwg = gx * gridDim.y;
  const int bid = blockIdx.y * gx + blockIdx.x;
  const int swz = (bid & 7) * (nwg >> 3) + (bid >> 3);
  const int m0 = (swz / gx) * 256;
  const int n0 = (swz % gx) * 256;

  const ushort* gA = A + (size_t)m0 * K;
  const ushort* gB = Bw + (size_t)n0 * K;
  const int NT = K >> 6;

  // -------- staging constants (8 gloads/thread/tile, same layout as R7) ------
  const int rh0  = t >> 3;                                 // row-in-half, chunk0
  const int slot = t & 7;
  const int gkhw = ((slot << 4) ^ ((rh0 & 7) << 4)) >> 1;  // inv-swizzled k (hw)
  const int growB0 = (rh0 >> 5) * 64 + (rh0 & 31);
  const uint dA = (uint)(rh0 * 64 + slot * 8);             // + mh*8192 + c*4096
  const uint dB = (uint)(32768 + rh0 * 64 + slot * 8);
  const ushort* pA = gA + (size_t)rh0 * K + gkhw;
  const ushort* pB = gB + (size_t)growB0 * K + gkhw;

  auto STAGE_ALL = [&](int parn, size_t ko){
    const uint dp = (uint)(parn * 16384);
    gload16(pA + ko,                   &lds[dA + dp]);          // A mh0 c0
    gload16(pA + 128 * (size_t)K + ko, &lds[dA + dp + 4096]);   // A mh0 c1
    gload16(pA + 64 * (size_t)K + ko,  &lds[dA + dp + 8192]);   // A mh1 c0
    gload16(pA + 192 * (size_t)K + ko, &lds[dA + dp + 12288]);  // A mh1 c1
    gload16(pB + ko,                   &lds[dB + dp]);          // B nh0 c0
    gload16(pB + 128 * (size_t)K + ko, &lds[dB + dp + 4096]);   // B nh0 c1
    gload16(pB + 32 * (size_t)K + ko,  &lds[dB + dp + 8192]);   // B nh1 c0
    gload16(pB + 160 * (size_t)K + ko, &lds[dB + dp + 12288]);  // B nh1 c1
  };

  // -------- fragment-read bases (hw indices; ks XOR baked into 4 bases) ------
  const int swb = (ln15 & 7) << 4;   // byte swizzle (row&7 == ln15&7 for all m,n)
  const int hA0 = (wm * 128 + ln15) * 64 + (((lnHi * 16)      ^ swb) >> 1);
  const int hA1 = (wm * 128 + ln15) * 64 + (((64 + lnHi * 16) ^ swb) >> 1);
  const int hB0 = 32768 + (wn * 32 + ln15) * 64 + (((lnHi * 16)      ^ swb) >> 1);
  const int hB1 = 32768 + (wn * 32 + ln15) * 64 + (((64 + lnHi * 16) ^ swb) >> 1);

  f32x4 acc[8][4] = {};

  auto TILE = [&](int PAR, size_t ko_next){
    asm volatile("s_waitcnt vmcnt(0)" ::: "memory");
    __builtin_amdgcn_s_barrier();
    f16x8 af0[8], af1[8], bf0[4], bf1[4];
#pragma unroll
    for (int m = 0; m < 8; ++m)
      af0[m] = *(const f16x8*)&lds[hA0 + PAR * 16384 + m * 1024];
#pragma unroll
    for (int j = 0; j < 4; ++j)
      bf0[j] = *(const f16x8*)&lds[hB0 + PAR * 16384 + (j >> 1) * 8192 + (j & 1) * 1024];
#pragma unroll
    for (int m = 0; m < 8; ++m)
      af1[m] = *(const f16x8*)&lds[hA1 + PAR * 16384 + m * 1024];
#pragma unroll
    for (int j = 0; j < 4; ++j)
      bf1[j] = *(const f16x8*)&lds[hB1 + PAR * 16384 + (j >> 1) * 8192 + (j & 1) * 1024];
    STAGE_ALL(PAR ^ 1, ko_next);
    __builtin_amdgcn_sched_barrier(0);
    __builtin_amdgcn_s_setprio(1);
#pragma unroll
    for (int m = 0; m < 8; ++m)
#pragma unroll
      for (int j = 0; j < 4; ++j)
        acc[m][j] = __builtin_amdgcn_mfma_f32_16x16x32_f16(af0[m], bf0[j], acc[m][j], 0, 0, 0);
#pragma unroll
    for (int m = 0; m < 8; ++m)
#pragma unroll
      for (int j = 0; j < 4; ++j)
        acc[m][j] = __builtin_amdgcn_mfma_f32_16x16x32_f16(af1[m], bf1[j], acc[m][j], 0, 0, 0);
    __builtin_amdgcn_s_setprio(0);
  };

  // prologue: stage tile 0 into plane 0
  STAGE_ALL(0, 0);
  for (int uu = 0; uu < NT; uu += 2){
    const size_t k1 = (size_t)(uu + 1) * 64;
    const size_t k2 = (size_t)((uu + 2 < NT) ? (uu + 2) * 64 : 0);  // wrap: harmless
    TILE(0, k1);
    TILE(1, k2);
  }
  __syncthreads();  // drain wrap-stages + publish before LDS reuse

  // ---- epilogue: act -> fp16 -> LDS [256][256] (XOR swizzle) -> coalesced stores --
  const int rowbase = wm * 128 + lnHi * 4;
  const int colbase = wn * 64 + ln15;
#pragma unroll
  for (int j = 0; j < 4; ++j){
    const int col = colbase + j * 16;
    const float bv = bias[n0 + col];
#pragma unroll
    for (int i = 0; i < 8; ++i){
#pragma unroll
      for (int r = 0; r < 4; ++r){
        const int row = rowbase + i * 16 + r;
        const float v = acc[i][j][r] + bv;
        float a;
        if (MODE == 0){
          const float th = 1.f - 2.f / (__expf(2.f * v) + 1.f);  // tanh(v)
          a = v > 0.f ? v * 0.9f + th * 0.1f : th * 0.5f;
        } else {
          a = v > 0.f ? v : 0.f;
        }
        const _Float16 h = (_Float16)a;
        lds[row * 256 + (col ^ ((row & 7) << 3))] = __builtin_bit_cast(ushort, h);
      }
    }
  }
  __syncthreads();
#pragma unroll
  for (int it = 0; it < 16; ++it){
    const int chunk = it * 512 + t;            // 256 rows x 32 chunks of 8 halfwords
    const int row = chunk >> 5, g = chunk & 31;
    const s16x8 vv = *(const s16x8*)&lds[row * 256 + ((g ^ (row & 7)) << 3)];
    *(s16x8*)&out[(size_t)(m0 + row) * N + n0 + (g << 3)] = vv;
  }
}

// ---------------- tiny GEMM3: out[32768][10] = h2 @ W3 + b3 (fp32 vector) ---------
__global__ void gemm3(const ushort* __restrict__ h2, const float* __restrict__ W3T,
                      const float* __restrict__ b3, float* __restrict__ out){
  const int lane = threadIdx.x & 63;
  const int row = blockIdx.x * 4 + (threadIdx.x >> 6);  // one wave per row
  const f16x8 hv = *(const f16x8*)(h2 + (size_t)row * 512 + lane * 8);
  float hf[8];
#pragma unroll
  for (int j = 0; j < 8; ++j) hf[j] = (float)hv[j];
  float acc[10];
#pragma unroll
  for (int c = 0; c < 10; ++c){
    const f32x4 w0 = *(const f32x4*)(W3T + c * 512 + lane * 8);
    const f32x4 w1 = *(const f32x4*)(W3T + c * 512 + lane * 8 + 4);
    float a = 0.f;
#pragma unroll
    for (int j = 0; j < 4; ++j) a += hf[j] * w0[j];
#pragma unroll
    for (int j = 0; j < 4; ++j) a += hf[4 + j] * w1[j];
    acc[c] = a;
  }
#pragma unroll
  for (int off = 32; off; off >>= 1)
#pragma unroll
    for (int c = 0; c < 10; ++c) acc[c] += __shfl_xor(acc[c], off);
  if (lane == 0){
#pragma unroll
    for (int c = 0; c < 10; ++c) out[(size_t)row * 10 + c] = acc[c] + b3[c];
  }
}

extern "C" void kernel_launch(void* const* d_in, const int* in_sizes, int n_in,
                              void* d_out, int out_size, void* d_ws, size_t ws_size,
                              hipStream_t stream){
  const float* x  = (const float*)d_in[0];
  const float* W1 = (const float*)d_in[1];
  const float* b1 = (const float*)d_in[2];
  const float* W2 = (const float*)d_in[3];
  const float* b2 = (const float*)d_in[4];
  const float* W3 = (const float*)d_in[5];
  const float* b3 = (const float*)d_in[6];
  float* out = (float*)d_out;

  const int B = 32768, Din = 512, H = 1024, Hh = 512;
  char* ws = (char*)d_ws;
  const size_t MB = (size_t)1 << 20;
  // ws layout (~99 MB):
  ushort* h1  = (ushort*)(ws);            // 64 MB  (32768 x 1024 fp16)
  ushort* xf  = (ushort*)(ws + 64 * MB);  // 32 MB  (32768 x 512 fp16; reused as h2)
  ushort* h2  = xf;
  ushort* W1T = (ushort*)(ws + 96 * MB);  // 1 MB   (1024 x 512 fp16)
  ushort* W2T = (ushort*)(ws + 97 * MB);  // 1 MB   (512 x 1024 fp16)
  float*  W3T = (float*)(ws + 98 * MB);   // 20 KB  (10 x 512 f32)

  convert_f16<<<(B * Din / 4 + 255) / 256, 256, 0, stream>>>(x, xf, B * Din / 4);
  transpose_f16<<<dim3(H / 32, Din / 32), 256, 0, stream>>>(W1, W1T, Din, H);
  transpose_f16<<<dim3(Hh / 32, H / 32), 256, 0, stream>>>(W2, W2T, H, Hh);
  transpose_w3<<<1, 512, 0, stream>>>(W3, W3T);

  gemm_f16_256<0><<<dim3(H / 256, B / 256), 512, 0, stream>>>(xf, W1T, b1, h1, H, Din);
  gemm_f16_256<1><<<dim3(Hh / 256, B / 256), 512, 0, stream>>>(h1, W2T, b2, h2, Hh, H);
  gemm3<<<B / 4, 256, 0, stream>>>(h2, W3T, b3, out);
}

// Round 10
// 153.308 us; speedup vs baseline: 1.1507x; 1.1507x over previous
//
#include <hip/hip_runtime.h>
#include <hip/hip_bf16.h>
#include <hip/hip_fp16.h>
#include <cstdint>

typedef __attribute__((ext_vector_type(8))) short s16x8;
typedef __attribute__((ext_vector_type(4))) short s16x4;
typedef __attribute__((ext_vector_type(8))) _Float16 f16x8;
typedef __attribute__((ext_vector_type(4))) _Float16 f16x4;
typedef __attribute__((ext_vector_type(4))) float f32x4;

__device__ __forceinline__ void gload16(const void* g, void* l){
  __builtin_amdgcn_global_load_lds((const __attribute__((address_space(1))) void*)g,
                                   (__attribute__((address_space(3))) void*)l, 16, 0, 0);
}

// ---------------- pre-pass: fp32 -> fp16 ----------------
__global__ void convert_f16(const float* __restrict__ in, ushort* __restrict__ out, int n4){
  int i = blockIdx.x * blockDim.x + threadIdx.x;
  if (i >= n4) return;
  const f32x4 v = ((const f32x4*)in)[i];
  f16x4 o;
#pragma unroll
  for (int j = 0; j < 4; ++j) o[j] = (_Float16)v[j];
  ((f16x4*)out)[i] = o;
}

// transpose + convert: in[K][N] f32 -> outT[N][K] fp16
__global__ void transpose_f16(const float* __restrict__ in, ushort* __restrict__ outT,
                              int K, int N){
  __shared__ float tile[32][33];
  const int kb = blockIdx.y * 32, nb = blockIdx.x * 32;
  const int tx = threadIdx.x & 31, ty = threadIdx.x >> 5;  // ty: 0..7
#pragma unroll
  for (int r = 0; r < 32; r += 8)
    tile[ty + r][tx] = in[(size_t)(kb + ty + r) * N + nb + tx];
  __syncthreads();
#pragma unroll
  for (int r = 0; r < 32; r += 8){
    const float v = tile[tx][ty + r];
    const _Float16 h = (_Float16)v;
    outT[(size_t)(nb + ty + r) * K + kb + tx] = __builtin_bit_cast(ushort, h);
  }
}

// W3 (512x10 f32) -> W3T (10x512 f32)
__global__ void transpose_w3(const float* __restrict__ W3, float* __restrict__ W3T){
  const int k = threadIdx.x;  // 512 threads
#pragma unroll
  for (int c = 0; c < 10; ++c) W3T[c * 512 + k] = W3[k * 10 + c];
}

// ---- 256x256-tile fp16 GEMM: minimal sync, 2 read/MFMA groups per K-tile -----
// 8 waves (2M x 4N), per-wave 128x64 output. LDS 128 KB double-buffered:
//   A plane p at hw p*16384 (half mh at +mh*8192), B at 32768 + p*16384.
// Per K-tile u (plane par=u&1):
//   vmcnt(0); s_barrier       // tile-u published; WAR-safe (all prior-tile
//                             // reads completed before their MFMAs pre-barrier)
//   12 ds_read (ks0 frags) ; 8 global_load_lds (tile u+1 -> other plane)
//   32 MFMA (ks0)             // compiler inserts minimal lgkm waits
//   sched_barrier(0)          // keep ks1 reads below cluster0 (VGPR liveness)
//   12 ds_read (ks1 frags) ; 32 MFMA (ks1)
// Last tile peeled (no stage). Only 8 loads ever in flight.
template<int MODE>
__global__ __launch_bounds__(512, 2)
void gemm_f16_256(const ushort* __restrict__ A, const ushort* __restrict__ Bw,
                  const float* __restrict__ bias, ushort* __restrict__ out,
                  int N, int K)
{
  __shared__ ushort lds[65536];
  const int t = threadIdx.x;
  const int lane = t & 63;
  const int w = t >> 6;
  const int wm = w >> 2, wn = w & 3;       // wave grid 2(M) x 4(N)
  const int ln15 = lane & 15, lnHi = lane >> 4;

  // XCD-aware bijective swizzle (nwg divisible by 8)
  const int gx = gridDim.x;
  const int nwg = gx * gridDim.y;
  const int bid = blockIdx.y * gx + blockIdx.x;
  const int swz = (bid & 7) * (nwg >> 3) + (bid >> 3);
  const int m0 = (swz / gx) * 256;
  const int n0 = (swz % gx) * 256;

  const ushort* gA = A + (size_t)m0 * K;
  const ushort* gB = Bw + (size_t)n0 * K;
  const int NT = K >> 6;

  // -------- staging constants (8 gloads/thread/tile) --------
  const int rh0  = t >> 3;                                 // row-in-half, chunk0
  const int slot = t & 7;
  const int gkhw = ((slot << 4) ^ ((rh0 & 7) << 4)) >> 1;  // inv-swizzled k (hw)
  const int growB0 = (rh0 >> 5) * 64 + (rh0 & 31);
  const uint dA = (uint)(rh0 * 64 + slot * 8);             // + mh*8192 + c*4096
  const uint dB = (uint)(32768 + rh0 * 64 + slot * 8);
  const ushort* pA = gA + (size_t)rh0 * K + gkhw;
  const ushort* pB = gB + (size_t)growB0 * K + gkhw;

  auto STAGE_ALL = [&](int parn, size_t ko){
    const uint dp = (uint)(parn * 16384);
    gload16(pA + ko,                   &lds[dA + dp]);          // A mh0 c0
    gload16(pA + 128 * (size_t)K + ko, &lds[dA + dp + 4096]);   // A mh0 c1
    gload16(pA + 64 * (size_t)K + ko,  &lds[dA + dp + 8192]);   // A mh1 c0
    gload16(pA + 192 * (size_t)K + ko, &lds[dA + dp + 12288]);  // A mh1 c1
    gload16(pB + ko,                   &lds[dB + dp]);          // B nh0 c0
    gload16(pB + 128 * (size_t)K + ko, &lds[dB + dp + 4096]);   // B nh0 c1
    gload16(pB + 32 * (size_t)K + ko,  &lds[dB + dp + 8192]);   // B nh1 c0
    gload16(pB + 160 * (size_t)K + ko, &lds[dB + dp + 12288]);  // B nh1 c1
  };

  // -------- fragment-read bases (hw indices; ks XOR baked into bases) --------
  const int swb = (ln15 & 7) << 4;   // byte swizzle (row&7 == ln15&7 for all m,n)
  const int hA0 = (wm * 128 + ln15) * 64 + (((lnHi * 16)      ^ swb) >> 1);
  const int hA1 = (wm * 128 + ln15) * 64 + (((64 + lnHi * 16) ^ swb) >> 1);
  const int hB0 = 32768 + (wn * 32 + ln15) * 64 + (((lnHi * 16)      ^ swb) >> 1);
  const int hB1 = 32768 + (wn * 32 + ln15) * 64 + (((64 + lnHi * 16) ^ swb) >> 1);

  f32x4 acc[8][4] = {};

  auto TILE = [&](int PAR, size_t ko_next, bool do_stage){
    asm volatile("s_waitcnt vmcnt(0)" ::: "memory");
    __builtin_amdgcn_s_barrier();
    const int pb = PAR * 16384;
    {
      f16x8 af[8], bfv[4];
#pragma unroll
      for (int m = 0; m < 8; ++m)
        af[m] = *(const f16x8*)&lds[hA0 + pb + m * 1024];
#pragma unroll
      for (int j = 0; j < 4; ++j)
        bfv[j] = *(const f16x8*)&lds[hB0 + pb + (j >> 1) * 8192 + (j & 1) * 1024];
      if (do_stage) STAGE_ALL(PAR ^ 1, ko_next);
      __builtin_amdgcn_s_setprio(1);
#pragma unroll
      for (int m = 0; m < 8; ++m)
#pragma unroll
        for (int j = 0; j < 4; ++j)
          acc[m][j] = __builtin_amdgcn_mfma_f32_16x16x32_f16(af[m], bfv[j], acc[m][j], 0, 0, 0);
      __builtin_amdgcn_s_setprio(0);
    }
    __builtin_amdgcn_sched_barrier(0);  // keep ks1 reads below cluster0
    {
      f16x8 af[8], bfv[4];
#pragma unroll
      for (int m = 0; m < 8; ++m)
        af[m] = *(const f16x8*)&lds[hA1 + pb + m * 1024];
#pragma unroll
      for (int j = 0; j < 4; ++j)
        bfv[j] = *(const f16x8*)&lds[hB1 + pb + (j >> 1) * 8192 + (j & 1) * 1024];
      __builtin_amdgcn_s_setprio(1);
#pragma unroll
      for (int m = 0; m < 8; ++m)
#pragma unroll
        for (int j = 0; j < 4; ++j)
          acc[m][j] = __builtin_amdgcn_mfma_f32_16x16x32_f16(af[m], bfv[j], acc[m][j], 0, 0, 0);
      __builtin_amdgcn_s_setprio(0);
    }
  };

  // prologue: stage tile 0 into plane 0
  STAGE_ALL(0, 0);
  for (int u = 0; u < NT; ++u)
    TILE(u & 1, (size_t)(u + 1) * 64, u + 1 < NT);

  __syncthreads();  // publish before LDS reuse (no outstanding gloads)

  // ---- epilogue: act -> fp16 -> LDS [256][256] (XOR swizzle) -> coalesced stores --
  const int rowbase = wm * 128 + lnHi * 4;
  const int colbase = wn * 64 + ln15;
#pragma unroll
  for (int j = 0; j < 4; ++j){
    const int col = colbase + j * 16;
    const float bv = bias[n0 + col];
#pragma unroll
    for (int i = 0; i < 8; ++i){
#pragma unroll
      for (int r = 0; r < 4; ++r){
        const int row = rowbase + i * 16 + r;
        const float v = acc[i][j][r] + bv;
        float a;
        if (MODE == 0){
          const float th = 1.f - 2.f / (__expf(2.f * v) + 1.f);  // tanh(v)
          a = v > 0.f ? v * 0.9f + th * 0.1f : th * 0.5f;
        } else {
          a = v > 0.f ? v : 0.f;
        }
        const _Float16 h = (_Float16)a;
        lds[row * 256 + (col ^ ((row & 7) << 3))] = __builtin_bit_cast(ushort, h);
      }
    }
  }
  __syncthreads();
#pragma unroll
  for (int it = 0; it < 16; ++it){
    const int chunk = it * 512 + t;            // 256 rows x 32 chunks of 8 halfwords
    const int row = chunk >> 5, g = chunk & 31;
    const s16x8 vv = *(const s16x8*)&lds[row * 256 + ((g ^ (row & 7)) << 3)];
    *(s16x8*)&out[(size_t)(m0 + row) * N + n0 + (g << 3)] = vv;
  }
}

// ---------------- tiny GEMM3: out[32768][10] = h2 @ W3 + b3 (fp32 vector) ---------
__global__ void gemm3(const ushort* __restrict__ h2, const float* __restrict__ W3T,
                      const float* __restrict__ b3, float* __restrict__ out){
  const int lane = threadIdx.x & 63;
  const int row = blockIdx.x * 4 + (threadIdx.x >> 6);  // one wave per row
  const f16x8 hv = *(const f16x8*)(h2 + (size_t)row * 512 + lane * 8);
  float hf[8];
#pragma unroll
  for (int j = 0; j < 8; ++j) hf[j] = (float)hv[j];
  float acc[10];
#pragma unroll
  for (int c = 0; c < 10; ++c){
    const f32x4 w0 = *(const f32x4*)(W3T + c * 512 + lane * 8);
    const f32x4 w1 = *(const f32x4*)(W3T + c * 512 + lane * 8 + 4);
    float a = 0.f;
#pragma unroll
    for (int j = 0; j < 4; ++j) a += hf[j] * w0[j];
#pragma unroll
    for (int j = 0; j < 4; ++j) a += hf[4 + j] * w1[j];
    acc[c] = a;
  }
#pragma unroll
  for (int off = 32; off; off >>= 1)
#pragma unroll
    for (int c = 0; c < 10; ++c) acc[c] += __shfl_xor(acc[c], off);
  if (lane == 0){
#pragma unroll
    for (int c = 0; c < 10; ++c) out[(size_t)row * 10 + c] = acc[c] + b3[c];
  }
}

extern "C" void kernel_launch(void* const* d_in, const int* in_sizes, int n_in,
                              void* d_out, int out_size, void* d_ws, size_t ws_size,
                              hipStream_t stream){
  const float* x  = (const float*)d_in[0];
  const float* W1 = (const float*)d_in[1];
  const float* b1 = (const float*)d_in[2];
  const float* W2 = (const float*)d_in[3];
  const float* b2 = (const float*)d_in[4];
  const float* W3 = (const float*)d_in[5];
  const float* b3 = (const float*)d_in[6];
  float* out = (float*)d_out;

  const int B = 32768, Din = 512, H = 1024, Hh = 512;
  char* ws = (char*)d_ws;
  const size_t MB = (size_t)1 << 20;
  // ws layout (~99 MB):
  ushort* h1  = (ushort*)(ws);            // 64 MB  (32768 x 1024 fp16)
  ushort* xf  = (ushort*)(ws + 64 * MB);  // 32 MB  (32768 x 512 fp16; reused as h2)
  ushort* h2  = xf;
  ushort* W1T = (ushort*)(ws + 96 * MB);  // 1 MB   (1024 x 512 fp16)
  ushort* W2T = (ushort*)(ws + 97 * MB);  // 1 MB   (512 x 1024 fp16)
  float*  W3T = (float*)(ws + 98 * MB);   // 20 KB  (10 x 512 f32)

  convert_f16<<<(B * Din / 4 + 255) / 256, 256, 0, stream>>>(x, xf, B * Din / 4);
  transpose_f16<<<dim3(H / 32, Din / 32), 256, 0, stream>>>(W1, W1T, Din, H);
  transpose_f16<<<dim3(Hh / 32, H / 32), 256, 0, stream>>>(W2, W2T, H, Hh);
  transpose_w3<<<1, 512, 0, stream>>>(W3, W3T);

  gemm_f16_256<0><<<dim3(H / 256, B / 256), 512, 0, stream>>>(xf, W1T, b1, h1, H, Din);
  gemm_f16_256<1><<<dim3(Hh / 256, B / 256), 512, 0, stream>>>(h1, W2T, b2, h2, Hh, H);
  gemm3<<<B / 4, 256, 0, stream>>>(h2, W3T, b3, out);
}

// Round 11
// 149.352 us; speedup vs baseline: 1.1811x; 1.0265x over previous
//
#include <hip/hip_runtime.h>
#include <hip/hip_bf16.h>
#include <hip/hip_fp16.h>
#include <cstdint>

typedef __attribute__((ext_vector_type(8))) short s16x8;
typedef __attribute__((ext_vector_type(4))) short s16x4;
typedef __attribute__((ext_vector_type(8))) _Float16 f16x8;
typedef __attribute__((ext_vector_type(4))) _Float16 f16x4;
typedef __attribute__((ext_vector_type(4))) float f32x4;

__device__ __forceinline__ void gload16(const void* g, void* l){
  __builtin_amdgcn_global_load_lds((const __attribute__((address_space(1))) void*)g,
                                   (__attribute__((address_space(3))) void*)l, 16, 0, 0);
}

// ---------------- pre-pass: fp32 -> fp16 ----------------
__global__ void convert_f16(const float* __restrict__ in, ushort* __restrict__ out, int n4){
  int i = blockIdx.x * blockDim.x + threadIdx.x;
  if (i >= n4) return;
  const f32x4 v = ((const f32x4*)in)[i];
  f16x4 o;
#pragma unroll
  for (int j = 0; j < 4; ++j) o[j] = (_Float16)v[j];
  ((f16x4*)out)[i] = o;
}

// transpose + convert: in[K][N] f32 -> outT[N][K] fp16
__global__ void transpose_f16(const float* __restrict__ in, ushort* __restrict__ outT,
                              int K, int N){
  __shared__ float tile[32][33];
  const int kb = blockIdx.y * 32, nb = blockIdx.x * 32;
  const int tx = threadIdx.x & 31, ty = threadIdx.x >> 5;  // ty: 0..7
#pragma unroll
  for (int r = 0; r < 32; r += 8)
    tile[ty + r][tx] = in[(size_t)(kb + ty + r) * N + nb + tx];
  __syncthreads();
#pragma unroll
  for (int r = 0; r < 32; r += 8){
    const float v = tile[tx][ty + r];
    const _Float16 h = (_Float16)v;
    outT[(size_t)(nb + ty + r) * K + kb + tx] = __builtin_bit_cast(ushort, h);
  }
}

// W3 (512x10 f32) -> W3T (10x512 f32)
__global__ void transpose_w3(const float* __restrict__ W3, float* __restrict__ W3T){
  const int k = threadIdx.x;  // 512 threads
#pragma unroll
  for (int c = 0; c < 10; ++c) W3T[c * 512 + k] = W3[k * 10 + c];
}

// ---- 128x256-tile fp16 GEMM: 2 blocks/CU TLP (m97-style 2-barrier loop) ------
// A: M x K fp16 row-major.  B: N x K fp16 row-major (pre-transposed weights).
// 4 waves (1M x 4N), per-wave 128x64 output (acc 8x4 f32x4).
// LDS 64 KB block: main loop uses 48 KB single-buffered (A[128][64] hw 0..8191,
// B[256][64] hw 8192..24575, XOR-swizzled rows); epilogue reuses [128][256].
// Loop: syncthreads (WAR) ; 12 x global_load_lds ; syncthreads (publish, the
// compiler's vmcnt0 drain hides under the co-resident block's MFMA phase) ;
// ks0 reads+32 MFMA ; sched_barrier ; ks1 reads+32 MFMA.
// MODE 0: blend_act -> fp16 out.  MODE 1: relu -> fp16 out.
template<int MODE>
__global__ __launch_bounds__(256, 2)
void gemm_f16_128x256(const ushort* __restrict__ A, const ushort* __restrict__ Bw,
                      const float* __restrict__ bias, ushort* __restrict__ out,
                      int N, int K)
{
  __shared__ ushort lds[32768];  // 64 KB
  const int t = threadIdx.x;
  const int lane = t & 63;
  const int wn = t >> 6;                   // wave grid 1(M) x 4(N)
  const int ln15 = lane & 15, lnHi = lane >> 4;

  // XCD-aware bijective swizzle (nwg divisible by 8)
  const int gx = gridDim.x;
  const int nwg = gx * gridDim.y;
  const int bid = blockIdx.y * gx + blockIdx.x;
  const int swz = (bid & 7) * (nwg >> 3) + (bid >> 3);
  const int m0 = (swz / gx) * 128;
  const int n0 = (swz % gx) * 256;

  const ushort* gA = A + (size_t)m0 * K;
  const ushort* gB = Bw + (size_t)n0 * K;

  // -------- staging constants (12 gloads/thread/K-tile) --------
  const int rh0  = t >> 3;                                 // base row (0..31)
  const int slot = t & 7;
  const int gkhw = ((slot << 4) ^ ((rh0 & 7) << 4)) >> 1;  // inv-swizzled k (hw)
  const uint dA = (uint)(rh0 * 64 + slot * 8);             // + c*2048 per 32 rows
  const uint dB = (uint)(8192 + rh0 * 64 + slot * 8);
  const ushort* pA = gA + (size_t)rh0 * K + gkhw;
  const ushort* pB = gB + (size_t)rh0 * K + gkhw;

  // -------- fragment-read bases (hw; XOR swizzle baked in) --------
  const int swb = (ln15 & 7) << 4;                         // bytes, bits 4-6
  const int koff0 = ((lnHi * 16) ^ swb) >> 1;
  const int koff1 = koff0 ^ 32;                            // +64B (lnHi*16 < 64)
  const int hA = ln15 * 64;                                // + m*1024 + koff
  const int hB = 8192 + (wn * 64 + ln15) * 64;             // + j*1024 + koff

  f32x4 acc[8][4] = {};

  for (int kt = 0; kt < K; kt += 64){
    __syncthreads();                       // WAR: all reads of prev tile done
#pragma unroll
    for (int c = 0; c < 4; ++c)
      gload16(pA + (size_t)c * 32 * K + kt, &lds[dA + c * 2048]);
#pragma unroll
    for (int c = 0; c < 8; ++c)
      gload16(pB + (size_t)c * 32 * K + kt, &lds[dB + c * 2048]);
    __syncthreads();                       // publish (vmcnt0+lgkm drain)
    {
      f16x8 af[8], bfv[4];
#pragma unroll
      for (int m = 0; m < 8; ++m)
        af[m] = *(const f16x8*)&lds[hA + m * 1024 + koff0];
#pragma unroll
      for (int j = 0; j < 4; ++j)
        bfv[j] = *(const f16x8*)&lds[hB + j * 1024 + koff0];
      __builtin_amdgcn_s_setprio(1);
#pragma unroll
      for (int m = 0; m < 8; ++m)
#pragma unroll
        for (int j = 0; j < 4; ++j)
          acc[m][j] = __builtin_amdgcn_mfma_f32_16x16x32_f16(af[m], bfv[j], acc[m][j], 0, 0, 0);
      __builtin_amdgcn_s_setprio(0);
    }
    __builtin_amdgcn_sched_barrier(0);     // cap fragment liveness (R9 spill fix)
    {
      f16x8 af[8], bfv[4];
#pragma unroll
      for (int m = 0; m < 8; ++m)
        af[m] = *(const f16x8*)&lds[hA + m * 1024 + koff1];
#pragma unroll
      for (int j = 0; j < 4; ++j)
        bfv[j] = *(const f16x8*)&lds[hB + j * 1024 + koff1];
      __builtin_amdgcn_s_setprio(1);
#pragma unroll
      for (int m = 0; m < 8; ++m)
#pragma unroll
        for (int j = 0; j < 4; ++j)
          acc[m][j] = __builtin_amdgcn_mfma_f32_16x16x32_f16(af[m], bfv[j], acc[m][j], 0, 0, 0);
      __builtin_amdgcn_s_setprio(0);
    }
  }

  __syncthreads();  // all LDS reads done before epilogue overwrite

  // ---- epilogue: act -> fp16 -> LDS [128][256] (XOR swizzle) -> coalesced stores --
  const int rowbase = lnHi * 4;
  const int colbase = wn * 64 + ln15;
#pragma unroll
  for (int j = 0; j < 4; ++j){
    const int col = colbase + j * 16;
    const float bv = bias[n0 + col];
#pragma unroll
    for (int i = 0; i < 8; ++i){
#pragma unroll
      for (int r = 0; r < 4; ++r){
        const int row = rowbase + i * 16 + r;
        const float v = acc[i][j][r] + bv;
        float a;
        if (MODE == 0){
          const float th = 1.f - 2.f / (__expf(2.f * v) + 1.f);  // tanh(v)
          a = v > 0.f ? v * 0.9f + th * 0.1f : th * 0.5f;
        } else {
          a = v > 0.f ? v : 0.f;
        }
        const _Float16 h = (_Float16)a;
        lds[row * 256 + (col ^ ((row & 7) << 3))] = __builtin_bit_cast(ushort, h);
      }
    }
  }
  __syncthreads();
#pragma unroll
  for (int it = 0; it < 16; ++it){
    const int chunk = it * 256 + t;            // 128 rows x 32 chunks of 8 halfwords
    const int row = chunk >> 5, g = chunk & 31;
    const s16x8 vv = *(const s16x8*)&lds[row * 256 + ((g ^ (row & 7)) << 3)];
    *(s16x8*)&out[(size_t)(m0 + row) * N + n0 + (g << 3)] = vv;
  }
}

// ---------------- tiny GEMM3: out[32768][10] = h2 @ W3 + b3 (fp32 vector) ---------
__global__ void gemm3(const ushort* __restrict__ h2, const float* __restrict__ W3T,
                      const float* __restrict__ b3, float* __restrict__ out){
  const int lane = threadIdx.x & 63;
  const int row = blockIdx.x * 4 + (threadIdx.x >> 6);  // one wave per row
  const f16x8 hv = *(const f16x8*)(h2 + (size_t)row * 512 + lane * 8);
  float hf[8];
#pragma unroll
  for (int j = 0; j < 8; ++j) hf[j] = (float)hv[j];
  float acc[10];
#pragma unroll
  for (int c = 0; c < 10; ++c){
    const f32x4 w0 = *(const f32x4*)(W3T + c * 512 + lane * 8);
    const f32x4 w1 = *(const f32x4*)(W3T + c * 512 + lane * 8 + 4);
    float a = 0.f;
#pragma unroll
    for (int j = 0; j < 4; ++j) a += hf[j] * w0[j];
#pragma unroll
    for (int j = 0; j < 4; ++j) a += hf[4 + j] * w1[j];
    acc[c] = a;
  }
#pragma unroll
  for (int off = 32; off; off >>= 1)
#pragma unroll
    for (int c = 0; c < 10; ++c) acc[c] += __shfl_xor(acc[c], off);
  if (lane == 0){
#pragma unroll
    for (int c = 0; c < 10; ++c) out[(size_t)row * 10 + c] = acc[c] + b3[c];
  }
}

extern "C" void kernel_launch(void* const* d_in, const int* in_sizes, int n_in,
                              void* d_out, int out_size, void* d_ws, size_t ws_size,
                              hipStream_t stream){
  const float* x  = (const float*)d_in[0];
  const float* W1 = (const float*)d_in[1];
  const float* b1 = (const float*)d_in[2];
  const float* W2 = (const float*)d_in[3];
  const float* b2 = (const float*)d_in[4];
  const float* W3 = (const float*)d_in[5];
  const float* b3 = (const float*)d_in[6];
  float* out = (float*)d_out;

  const int B = 32768, Din = 512, H = 1024, Hh = 512;
  char* ws = (char*)d_ws;
  const size_t MB = (size_t)1 << 20;
  // ws layout (~99 MB):
  ushort* h1  = (ushort*)(ws);            // 64 MB  (32768 x 1024 fp16)
  ushort* xf  = (ushort*)(ws + 64 * MB);  // 32 MB  (32768 x 512 fp16; reused as h2)
  ushort* h2  = xf;
  ushort* W1T = (ushort*)(ws + 96 * MB);  // 1 MB   (1024 x 512 fp16)
  ushort* W2T = (ushort*)(ws + 97 * MB);  // 1 MB   (512 x 1024 fp16)
  float*  W3T = (float*)(ws + 98 * MB);   // 20 KB  (10 x 512 f32)

  convert_f16<<<(B * Din / 4 + 255) / 256, 256, 0, stream>>>(x, xf, B * Din / 4);
  transpose_f16<<<dim3(H / 32, Din / 32), 256, 0, stream>>>(W1, W1T, Din, H);
  transpose_f16<<<dim3(Hh / 32, H / 32), 256, 0, stream>>>(W2, W2T, H, Hh);
  transpose_w3<<<1, 512, 0, stream>>>(W3, W3T);

  gemm_f16_128x256<0><<<dim3(H / 256, B / 128), 256, 0, stream>>>(xf, W1T, b1, h1, H, Din);
  gemm_f16_128x256<1><<<dim3(Hh / 256, B / 128), 256, 0, stream>>>(h1, W2T, b2, h2, Hh, H);
  gemm3<<<B / 4, 256, 0, stream>>>(h2, W3T, b3, out);
}